// Round 9
// baseline (557.059 us; speedup 1.0000x reference)
//
#include <hip/hip_runtime.h>
#include <hip/hip_bf16.h>

#define N_USERS   100000
#define N_ITEMS   50000
#define N_NODES_C 150000
#define EMB       64
#define N_ELEM    (N_NODES_C * EMB)   // 9,600,000
#define BKT_SHIFT 9
#define NBKT      ((N_NODES_C + 511) >> 9)              // 293
#define BKT_CAP   20480                                 // mean 16384 + 32 sigma
#define CH_EDGES  4096
#define EPT       16                                    // edges/thread, scatter_bucket
#define NCB       10                                    // col blocks (col>>14, 2MB x each)

// ---- dtype detection (fp32 vs bf16-packed) + zero bucket tails ----
__global__ void detect_and_zero(const unsigned int* __restrict__ emb_u32,
                                const unsigned int* __restrict__ vals_u32,
                                int* __restrict__ flags,
                                int* __restrict__ tails) {
    int t = threadIdx.x;
    for (int b = t; b < NBKT; b += 256) tails[b] = 0;
    int cnt_emb = 0, cnt_vals = 0;
    for (int k = t; k < 1024; k += 256) {
        unsigned e = (emb_u32[k] >> 7) & 0xFFu;
        cnt_emb += (e >= 100u && e <= 127u) ? 1 : 0;
        cnt_vals += (vals_u32[k] >> 15) & 1u;
    }
    __shared__ int s0[256], s1[256];
    s0[t] = cnt_emb; s1[t] = cnt_vals;
    __syncthreads();
    for (int s = 128; s > 0; s >>= 1) {
        if (t < s) { s0[t] += s0[t + s]; s1[t] += s1[t + s]; }
        __syncthreads();
    }
    if (t == 0) {
        flags[0] = (s0[0] > 512) ? 1 : 0;   // emb/out bf16?
        flags[1] = (s1[0] > 100) ? 0 : 1;   // vals bf16?
    }
}

__device__ __forceinline__ float load_f(const void* base, size_t i, int is_bf16) {
    if (is_bf16) return __bfloat162float(((const __hip_bfloat16*)base)[i]);
    return ((const float*)base)[i];
}
__device__ __forceinline__ unsigned int bf16_bits(float f) {
    __hip_bfloat16 h = __float2bfloat16(f);
    return (unsigned int)reinterpret_cast<unsigned short&>(h);
}
__device__ __forceinline__ float lo_bf(unsigned int u) {
    return __uint_as_float(u << 16);
}
__device__ __forceinline__ float hi_bf(unsigned int u) {
    return __uint_as_float(u & 0xFFFF0000u);
}

// ---- init: h0 = ego (bf16). d_out untouched until the last spmm. ----
__global__ void init_kernel(const void* __restrict__ eu,
                            const void* __restrict__ ei,
                            __hip_bfloat16* __restrict__ h0,
                            const int* __restrict__ flags) {
    int i = blockIdx.x * blockDim.x + threadIdx.x;
    if (i >= N_ELEM) return;
    int ebf = flags[0];
    float f = (i < N_USERS * EMB) ? load_f(eu, i, ebf)
                                  : load_f(ei, i - N_USERS * EMB, ebf);
    h0[i] = __float2bfloat16(f);
}

// ---- bin edges into fixed-capacity buckets (packed u64), bulk tail claims ----
__global__ void scatter_bucket(const int* __restrict__ rows, const int* __restrict__ cols,
                               const void* __restrict__ vals,
                               unsigned long long* __restrict__ tmp,
                               int* __restrict__ tails, int nnz,
                               const int* __restrict__ flags) {
    __shared__ int lcnt[NBKT];
    __shared__ int lbase[NBKT];
    int t = threadIdx.x;
    for (int b = t; b < NBKT; b += 256) lcnt[b] = 0;
    __syncthreads();
    int base = blockIdx.x * CH_EDGES;
    int vbf = flags[1];
    unsigned long long pk[EPT];
    unsigned int br[EPT];
    #pragma unroll
    for (int i = 0; i < EPT; ++i) {
        int e = base + i * 256 + t;
        if (e < nnz) {
            int r = rows[e];
            int c = cols[e];
            float v = load_f(vals, (size_t)e, vbf);
            int bk = r >> BKT_SHIFT;
            int rk = atomicAdd(&lcnt[bk], 1);
            pk[i] = ((unsigned long long)(unsigned)r << 34)
                  | ((unsigned long long)(unsigned)c << 16)
                  | (unsigned long long)bf16_bits(v);
            br[i] = ((unsigned)bk << 16) | (unsigned)rk;
        } else {
            br[i] = 0xFFFFFFFFu;
        }
    }
    __syncthreads();
    for (int b = t; b < NBKT; b += 256)
        lbase[b] = lcnt[b] ? atomicAdd(&tails[b], lcnt[b]) : 0;
    __syncthreads();
    #pragma unroll
    for (int i = 0; i < EPT; ++i) {
        if (br[i] != 0xFFFFFFFFu) {
            int bk = br[i] >> 16, rk = br[i] & 0xFFFFu;
            int pos = lbase[bk] + rk;
            if (pos < BKT_CAP)
                tmp[(size_t)bk * BKT_CAP + pos] = pk[i];
        }
    }
}

// ---- exclusive scan of 293 bucket counts -> bktbase[0..NBKT] ----
__global__ void scan_bkt(const int* __restrict__ tails, int* __restrict__ bktbase) {
    __shared__ int l[512];
    int t = threadIdx.x;
    int v = (t < NBKT) ? tails[t] : 0;
    l[t] = v;
    __syncthreads();
    for (int off = 1; off < 512; off <<= 1) {
        int u = (t >= off) ? l[t - off] : 0;
        __syncthreads();
        l[t] += u;
        __syncthreads();
    }
    if (t < NBKT) bktbase[t] = l[t] - v;
    if (t == NBKT - 1) bktbase[NBKT] = l[t];
}

// ---- one block per bucket: count per (row, col-block), LDS scan -> row_ptr
//      slice, scatter into CSR order with col-block ordering inside each row
//      (gathers then sweep 2MB x-windows that stay L2-resident). ----
__global__ void bucket_csr(const unsigned long long* __restrict__ tmp,
                           int2* __restrict__ edges,
                           const int* __restrict__ tails,
                           const int* __restrict__ bktbase,
                           int* __restrict__ row_ptr) {
    __shared__ int cnt[512 * NCB];      // 20 KB: key = rloc*NCB + colblock
    __shared__ int part[512];
    int b = blockIdx.x, t = threadIdx.x;
    int rowbase = b << BKT_SHIFT;
    int nrows = N_NODES_C - rowbase; if (nrows > 512) nrows = 512;
    int n = tails[b];
    if (n > BKT_CAP) n = BKT_CAP;
    const unsigned long long* src = tmp + (size_t)b * BKT_CAP;
    int obase = bktbase[b];
    #pragma unroll
    for (int j = 0; j < NCB; ++j) cnt[t * NCB + j] = 0;
    __syncthreads();
    for (int e = t; e < n; e += 512) {
        unsigned long long p = src[e];
        int rloc = (int)(p >> 34) - rowbase;
        int cb = (int)((p >> 16) & 0x3FFFFu) >> 14;
        atomicAdd(&cnt[rloc * NCB + cb], 1);
    }
    __syncthreads();
    // serial prefix over this thread's NCB keys, then block scan of totals
    int loc[NCB];
    int s = 0;
    #pragma unroll
    for (int j = 0; j < NCB; ++j) { loc[j] = s; s += cnt[t * NCB + j]; }
    part[t] = s;
    __syncthreads();
    for (int o = 1; o < 512; o <<= 1) {
        int u = (t >= o) ? part[t - o] : 0;
        __syncthreads();
        part[t] += u;
        __syncthreads();
    }
    int excl = part[t] - s;             // exclusive row start within bucket
    __syncthreads();
    #pragma unroll
    for (int j = 0; j < NCB; ++j) cnt[t * NCB + j] = obase + excl + loc[j];
    if (t < nrows) row_ptr[rowbase + t] = obase + excl;
    if (b == NBKT - 1 && t == 0) row_ptr[N_NODES_C] = obase + n;
    __syncthreads();
    for (int e = t; e < n; e += 512) {
        unsigned long long p = src[e];
        int rloc = (int)(p >> 34) - rowbase;
        int c = (int)((p >> 16) & 0x3FFFFu);
        int pos = atomicAdd(&cnt[rloc * NCB + (c >> 14)], 1);
        edges[pos] = make_int2(c, (int)((unsigned)(p & 0xFFFFu) << 16));
    }
}

#define ACC8(v, g)                      \
    a0 += (v) * lo_bf((g).x);           \
    a1 += (v) * hi_bf((g).x);           \
    a2 += (v) * lo_bf((g).y);           \
    a3 += (v) * hi_bf((g).y);           \
    a4 += (v) * lo_bf((g).z);           \
    a5 += (v) * hi_bf((g).z);           \
    a6 += (v) * lo_bf((g).w);           \
    a7 += (v) * hi_bf((g).w);

// ---- CSR SpMM: one wave/row, 8 edge-slots (8 lanes x uint4 = full 128B row),
//      2x unroll -> 16 edges in flight. Butterfly reduce over slots.
//      last==0: y = A*x (bf16).  last==1: d_out = (h0+h1+h2+A*x)/4 (sole write).
__global__ void spmm8(const __hip_bfloat16* __restrict__ x,
                      __hip_bfloat16* __restrict__ y,
                      const int2* __restrict__ edges,
                      const int* __restrict__ row_ptr,
                      const __hip_bfloat16* __restrict__ h0,
                      const __hip_bfloat16* __restrict__ h1,
                      void* __restrict__ out,
                      const int* __restrict__ flags,
                      int last) {
    int row = blockIdx.x * 4 + (threadIdx.x >> 6);
    if (row >= N_NODES_C) return;
    int lane = threadIdx.x & 63;
    int slot = lane >> 3;       // edge slot 0..7
    int s    = lane & 7;        // elem octet: elems [8s, 8s+7]
    int beg = row_ptr[row], end = row_ptr[row + 1];
    float a0 = 0.f, a1 = 0.f, a2 = 0.f, a3 = 0.f,
          a4 = 0.f, a5 = 0.f, a6 = 0.f, a7 = 0.f;
    for (int e = beg; e < end; e += 16) {
        int iA = e + slot;
        int iB = e + 8 + slot;
        int2 edA = (iA < end) ? edges[iA] : make_int2(0, 0);
        int2 edB = (iB < end) ? edges[iB] : make_int2(0, 0);
        float vA = __int_as_float(edA.y);
        float vB = __int_as_float(edB.y);
        const uint4 gA = *reinterpret_cast<const uint4*>(
            x + ((size_t)(unsigned)edA.x << 6) + (s << 3));
        const uint4 gB = *reinterpret_cast<const uint4*>(
            x + ((size_t)(unsigned)edB.x << 6) + (s << 3));
        ACC8(vA, gA);
        ACC8(vB, gB);
    }
    #pragma unroll
    for (int m = 8; m < 64; m <<= 1) {
        a0 += __shfl_xor(a0, m, 64);
        a1 += __shfl_xor(a1, m, 64);
        a2 += __shfl_xor(a2, m, 64);
        a3 += __shfl_xor(a3, m, 64);
        a4 += __shfl_xor(a4, m, 64);
        a5 += __shfl_xor(a5, m, 64);
        a6 += __shfl_xor(a6, m, 64);
        a7 += __shfl_xor(a7, m, 64);
    }
    if (slot != 0) return;
    size_t base = ((size_t)row << 6) + (s << 3);
    if (!last) {
        uint4 o;
        o.x = bf16_bits(a0) | (bf16_bits(a1) << 16);
        o.y = bf16_bits(a2) | (bf16_bits(a3) << 16);
        o.z = bf16_bits(a4) | (bf16_bits(a5) << 16);
        o.w = bf16_bits(a6) | (bf16_bits(a7) << 16);
        *reinterpret_cast<uint4*>(y + base) = o;
    } else {
        const uint4 r0 = *reinterpret_cast<const uint4*>(h0 + base);
        const uint4 r1 = *reinterpret_cast<const uint4*>(h1 + base);
        const uint4 r2 = *reinterpret_cast<const uint4*>(x + base);  // x == h2
        float f0 = (lo_bf(r0.x) + lo_bf(r1.x) + lo_bf(r2.x) + a0) * 0.25f;
        float f1 = (hi_bf(r0.x) + hi_bf(r1.x) + hi_bf(r2.x) + a1) * 0.25f;
        float f2 = (lo_bf(r0.y) + lo_bf(r1.y) + lo_bf(r2.y) + a2) * 0.25f;
        float f3 = (hi_bf(r0.y) + hi_bf(r1.y) + hi_bf(r2.y) + a3) * 0.25f;
        float f4 = (lo_bf(r0.z) + lo_bf(r1.z) + lo_bf(r2.z) + a4) * 0.25f;
        float f5 = (hi_bf(r0.z) + hi_bf(r1.z) + hi_bf(r2.z) + a5) * 0.25f;
        float f6 = (lo_bf(r0.w) + lo_bf(r1.w) + lo_bf(r2.w) + a6) * 0.25f;
        float f7 = (hi_bf(r0.w) + hi_bf(r1.w) + hi_bf(r2.w) + a7) * 0.25f;
        if (flags[0]) {
            uint4 o;
            o.x = bf16_bits(f0) | (bf16_bits(f1) << 16);
            o.y = bf16_bits(f2) | (bf16_bits(f3) << 16);
            o.z = bf16_bits(f4) | (bf16_bits(f5) << 16);
            o.w = bf16_bits(f6) | (bf16_bits(f7) << 16);
            *reinterpret_cast<uint4*>((__hip_bfloat16*)out + base) = o;
        } else {
            float* op = (float*)out + base;
            *reinterpret_cast<float4*>(op)     = make_float4(f0, f1, f2, f3);
            *reinterpret_cast<float4*>(op + 4) = make_float4(f4, f5, f6, f7);
        }
    }
}

extern "C" void kernel_launch(void* const* d_in, const int* in_sizes, int n_in,
                              void* d_out, int out_size, void* d_ws, size_t ws_size,
                              hipStream_t stream) {
    const void* eu   = d_in[0];
    const void* ei   = d_in[1];
    const void* vals = d_in[2];
    const int*  rows = (const int*)d_in[3];
    const int*  cols = (const int*)d_in[4];
    const int nnz = in_sizes[2];

    // ws layout: h0..h2 (57.6MB) | edges (38.4MB) | tables | align8 tmp (48MB)
    __hip_bfloat16* h[3];
    h[0] = (__hip_bfloat16*)d_ws;
    h[1] = h[0] + N_ELEM;
    h[2] = h[1] + N_ELEM;
    int2* edges   = (int2*)(h[2] + N_ELEM);
    int* row_ptr  = (int*)(edges + nnz);                  // N_NODES_C + 1
    int* bktbase  = row_ptr + (N_NODES_C + 1);            // NBKT + 1
    int* tails    = bktbase + (NBKT + 1);                 // NBKT
    int* flags    = tails + NBKT;                         // 2
    char* pt = (char*)(flags + 2);
    unsigned long long* tmp =
        (unsigned long long*)(((uintptr_t)pt + 7) & ~(uintptr_t)7);  // NBKT*CAP u64

    detect_and_zero<<<1, 256, 0, stream>>>((const unsigned int*)eu,
                                           (const unsigned int*)vals, flags, tails);
    init_kernel<<<(N_ELEM + 255) / 256, 256, 0, stream>>>(eu, ei, h[0], flags);

    // CSR build: slot-bucket scatter -> bucket scan -> per-bucket CSR sort
    int nchunks = (nnz + CH_EDGES - 1) / CH_EDGES;
    scatter_bucket<<<nchunks, 256, 0, stream>>>(rows, cols, vals, tmp, tails, nnz, flags);
    scan_bkt<<<1, 512, 0, stream>>>(tails, bktbase);
    bucket_csr<<<NBKT, 512, 0, stream>>>(tmp, edges, tails, bktbase, row_ptr);

    // layers: h0 -> h1 -> h2 -> (fused final) d_out
    int nsb = (N_NODES_C + 3) / 4;
    spmm8<<<nsb, 256, 0, stream>>>(h[0], h[1], edges, row_ptr,
                                   nullptr, nullptr, nullptr, flags, 0);
    spmm8<<<nsb, 256, 0, stream>>>(h[1], h[2], edges, row_ptr,
                                   nullptr, nullptr, nullptr, flags, 0);
    spmm8<<<nsb, 256, 0, stream>>>(h[2], nullptr, edges, row_ptr,
                                   h[0], h[1], d_out, flags, 1);
}

// Round 11
// 520.225 us; speedup vs baseline: 1.0708x; 1.0708x over previous
//
#include <hip/hip_runtime.h>
#include <hip/hip_bf16.h>

#define N_USERS   100000
#define N_ITEMS   50000
#define N_NODES_C 150000
#define EMB       64
#define N_ELEM    (N_NODES_C * EMB)   // 9,600,000
#define BKT_SHIFT 9
#define NBKT      ((N_NODES_C + 511) >> 9)              // 293
#define BKT_CAP   20480                                 // mean 16384 + 32 sigma
#define CH_EDGES  4096
#define EPT       16                                    // edges/thread, scatter_bucket

typedef unsigned int u32x4 __attribute__((ext_vector_type(4)));

// ---- dtype detection (fp32 vs bf16-packed) + zero bucket tails ----
__global__ void detect_and_zero(const unsigned int* __restrict__ emb_u32,
                                const unsigned int* __restrict__ vals_u32,
                                int* __restrict__ flags,
                                int* __restrict__ tails) {
    int t = threadIdx.x;
    for (int b = t; b < NBKT; b += 256) tails[b] = 0;
    int cnt_emb = 0, cnt_vals = 0;
    for (int k = t; k < 1024; k += 256) {
        unsigned e = (emb_u32[k] >> 7) & 0xFFu;
        cnt_emb += (e >= 100u && e <= 127u) ? 1 : 0;
        cnt_vals += (vals_u32[k] >> 15) & 1u;
    }
    __shared__ int s0[256], s1[256];
    s0[t] = cnt_emb; s1[t] = cnt_vals;
    __syncthreads();
    for (int s = 128; s > 0; s >>= 1) {
        if (t < s) { s0[t] += s0[t + s]; s1[t] += s1[t + s]; }
        __syncthreads();
    }
    if (t == 0) {
        flags[0] = (s0[0] > 512) ? 1 : 0;   // emb/out bf16?
        flags[1] = (s1[0] > 100) ? 0 : 1;   // vals bf16?
    }
}

__device__ __forceinline__ float load_f(const void* base, size_t i, int is_bf16) {
    if (is_bf16) return __bfloat162float(((const __hip_bfloat16*)base)[i]);
    return ((const float*)base)[i];
}
__device__ __forceinline__ unsigned int bf16_bits(float f) {
    __hip_bfloat16 h = __float2bfloat16(f);
    return (unsigned int)reinterpret_cast<unsigned short&>(h);
}
__device__ __forceinline__ float lo_bf(unsigned int u) {
    return __uint_as_float(u << 16);
}
__device__ __forceinline__ float hi_bf(unsigned int u) {
    return __uint_as_float(u & 0xFFFF0000u);
}

// ---- init: h0 = ego (bf16). d_out untouched until the last spmm. ----
__global__ void init_kernel(const void* __restrict__ eu,
                            const void* __restrict__ ei,
                            __hip_bfloat16* __restrict__ h0,
                            const int* __restrict__ flags) {
    int i = blockIdx.x * blockDim.x + threadIdx.x;
    if (i >= N_ELEM) return;
    int ebf = flags[0];
    float f = (i < N_USERS * EMB) ? load_f(eu, i, ebf)
                                  : load_f(ei, i - N_USERS * EMB, ebf);
    h0[i] = __float2bfloat16(f);
}

// ---- bin edges into fixed-capacity buckets (packed u64), bulk tail claims ----
__global__ void scatter_bucket(const int* __restrict__ rows, const int* __restrict__ cols,
                               const void* __restrict__ vals,
                               unsigned long long* __restrict__ tmp,
                               int* __restrict__ tails, int nnz,
                               const int* __restrict__ flags) {
    __shared__ int lcnt[NBKT];
    __shared__ int lbase[NBKT];
    int t = threadIdx.x;
    for (int b = t; b < NBKT; b += 256) lcnt[b] = 0;
    __syncthreads();
    int base = blockIdx.x * CH_EDGES;
    int vbf = flags[1];
    unsigned long long pk[EPT];
    unsigned int br[EPT];
    #pragma unroll
    for (int i = 0; i < EPT; ++i) {
        int e = base + i * 256 + t;
        if (e < nnz) {
            int r = rows[e];
            int c = cols[e];
            float v = load_f(vals, (size_t)e, vbf);
            int bk = r >> BKT_SHIFT;
            int rk = atomicAdd(&lcnt[bk], 1);
            pk[i] = ((unsigned long long)(unsigned)r << 34)
                  | ((unsigned long long)(unsigned)c << 16)
                  | (unsigned long long)bf16_bits(v);
            br[i] = ((unsigned)bk << 16) | (unsigned)rk;
        } else {
            br[i] = 0xFFFFFFFFu;
        }
    }
    __syncthreads();
    for (int b = t; b < NBKT; b += 256)
        lbase[b] = lcnt[b] ? atomicAdd(&tails[b], lcnt[b]) : 0;
    __syncthreads();
    #pragma unroll
    for (int i = 0; i < EPT; ++i) {
        if (br[i] != 0xFFFFFFFFu) {
            int bk = br[i] >> 16, rk = br[i] & 0xFFFFu;
            int pos = lbase[bk] + rk;
            if (pos < BKT_CAP)
                tmp[(size_t)bk * BKT_CAP + pos] = pk[i];
        }
    }
}

// ---- exclusive scan of 293 bucket counts -> bktbase[0..NBKT] ----
__global__ void scan_bkt(const int* __restrict__ tails, int* __restrict__ bktbase) {
    __shared__ int l[512];
    int t = threadIdx.x;
    int v = (t < NBKT) ? tails[t] : 0;
    l[t] = v;
    __syncthreads();
    for (int off = 1; off < 512; off <<= 1) {
        int u = (t >= off) ? l[t - off] : 0;
        __syncthreads();
        l[t] += u;
        __syncthreads();
    }
    if (t < NBKT) bktbase[t] = l[t] - v;
    if (t == NBKT - 1) bktbase[NBKT] = l[t];
}

// ---- one block per bucket: count rows, LDS scan -> row_ptr slice,
//      scatter slot-region edges into exact CSR order (L2-local). ----
__global__ void bucket_csr(const unsigned long long* __restrict__ tmp,
                           int2* __restrict__ edges,
                           const int* __restrict__ tails,
                           const int* __restrict__ bktbase,
                           int* __restrict__ row_ptr) {
    __shared__ int cnt[512];
    __shared__ int off[512];
    int b = blockIdx.x, t = threadIdx.x;
    int rowbase = b << BKT_SHIFT;
    int nrows = N_NODES_C - rowbase; if (nrows > 512) nrows = 512;
    int n = tails[b];
    if (n > BKT_CAP) n = BKT_CAP;
    const unsigned long long* src = tmp + (size_t)b * BKT_CAP;
    int obase = bktbase[b];
    cnt[t] = 0;
    __syncthreads();
    for (int e = t; e < n; e += 512)
        atomicAdd(&cnt[(int)(src[e] >> 34) - rowbase], 1);
    __syncthreads();
    int v = cnt[t];
    off[t] = v;
    __syncthreads();
    for (int o = 1; o < 512; o <<= 1) {
        int u = (t >= o) ? off[t - o] : 0;
        __syncthreads();
        off[t] += u;
        __syncthreads();
    }
    int excl = off[t] - v;
    __syncthreads();
    off[t] = obase + excl;
    if (t < nrows) row_ptr[rowbase + t] = obase + excl;
    if (b == NBKT - 1 && t == 0) row_ptr[N_NODES_C] = obase + n;
    __syncthreads();
    for (int e = t; e < n; e += 512) {
        unsigned long long p = src[e];
        int rloc = (int)(p >> 34) - rowbase;
        int c = (int)((p >> 16) & 0x3FFFFu);
        int pos = atomicAdd(&off[rloc], 1);
        edges[pos] = make_int2(c, (int)((unsigned)(p & 0xFFFFu) << 16));
    }
}

#define ACC8(v, g)                      \
    a0 += (v) * lo_bf((g).x);           \
    a1 += (v) * hi_bf((g).x);           \
    a2 += (v) * lo_bf((g).y);           \
    a3 += (v) * hi_bf((g).y);           \
    a4 += (v) * lo_bf((g).z);           \
    a5 += (v) * hi_bf((g).z);           \
    a6 += (v) * lo_bf((g).w);           \
    a7 += (v) * hi_bf((g).w);

// ---- CSR SpMM: one wave/row, 8 edge-slots x uint4 (full 128B row per edge),
//      4 independent gather chains (32 edges in flight). Nontemporal edge
//      loads + y stores keep L2 for x. Butterfly reduce over slots.
//      last==0: y = A*x (bf16).  last==1: d_out = (h0+h1+h2+A*x)/4 (sole write).
__global__ void spmm8(const __hip_bfloat16* __restrict__ x,
                      __hip_bfloat16* __restrict__ y,
                      const unsigned long long* __restrict__ edges,
                      const int* __restrict__ row_ptr,
                      const __hip_bfloat16* __restrict__ h0,
                      const __hip_bfloat16* __restrict__ h1,
                      void* __restrict__ out,
                      const int* __restrict__ flags,
                      int last) {
    int row = blockIdx.x * 4 + (threadIdx.x >> 6);
    if (row >= N_NODES_C) return;
    int lane = threadIdx.x & 63;
    int slot = lane >> 3;       // edge slot 0..7
    int s    = lane & 7;        // elem octet: elems [8s, 8s+7]
    int beg = row_ptr[row], end = row_ptr[row + 1];
    float a0 = 0.f, a1 = 0.f, a2 = 0.f, a3 = 0.f,
          a4 = 0.f, a5 = 0.f, a6 = 0.f, a7 = 0.f;
    for (int e = beg; e < end; e += 32) {
        int iA = e + slot;
        int iB = iA + 8;
        int iC = iA + 16;
        int iD = iA + 24;
        unsigned long long pA = (iA < end) ? __builtin_nontemporal_load(edges + iA) : 0ULL;
        unsigned long long pB = (iB < end) ? __builtin_nontemporal_load(edges + iB) : 0ULL;
        unsigned long long pC = (iC < end) ? __builtin_nontemporal_load(edges + iC) : 0ULL;
        unsigned long long pD = (iD < end) ? __builtin_nontemporal_load(edges + iD) : 0ULL;
        const uint4 gA = *reinterpret_cast<const uint4*>(
            x + ((size_t)(unsigned)(pA & 0xFFFFFFFFu) << 6) + (s << 3));
        const uint4 gB = *reinterpret_cast<const uint4*>(
            x + ((size_t)(unsigned)(pB & 0xFFFFFFFFu) << 6) + (s << 3));
        const uint4 gC = *reinterpret_cast<const uint4*>(
            x + ((size_t)(unsigned)(pC & 0xFFFFFFFFu) << 6) + (s << 3));
        const uint4 gD = *reinterpret_cast<const uint4*>(
            x + ((size_t)(unsigned)(pD & 0xFFFFFFFFu) << 6) + (s << 3));
        float vA = __uint_as_float((unsigned)(pA >> 32));
        float vB = __uint_as_float((unsigned)(pB >> 32));
        float vC = __uint_as_float((unsigned)(pC >> 32));
        float vD = __uint_as_float((unsigned)(pD >> 32));
        ACC8(vA, gA);
        ACC8(vB, gB);
        ACC8(vC, gC);
        ACC8(vD, gD);
    }
    #pragma unroll
    for (int m = 8; m < 64; m <<= 1) {
        a0 += __shfl_xor(a0, m, 64);
        a1 += __shfl_xor(a1, m, 64);
        a2 += __shfl_xor(a2, m, 64);
        a3 += __shfl_xor(a3, m, 64);
        a4 += __shfl_xor(a4, m, 64);
        a5 += __shfl_xor(a5, m, 64);
        a6 += __shfl_xor(a6, m, 64);
        a7 += __shfl_xor(a7, m, 64);
    }
    if (slot != 0) return;
    size_t base = ((size_t)row << 6) + (s << 3);
    if (!last) {
        u32x4 o;
        o.x = bf16_bits(a0) | (bf16_bits(a1) << 16);
        o.y = bf16_bits(a2) | (bf16_bits(a3) << 16);
        o.z = bf16_bits(a4) | (bf16_bits(a5) << 16);
        o.w = bf16_bits(a6) | (bf16_bits(a7) << 16);
        __builtin_nontemporal_store(o, reinterpret_cast<u32x4*>(y + base));
    } else {
        const uint4 r0 = *reinterpret_cast<const uint4*>(h0 + base);
        const uint4 r1 = *reinterpret_cast<const uint4*>(h1 + base);
        const uint4 r2 = *reinterpret_cast<const uint4*>(x + base);  // x == h2
        float f0 = (lo_bf(r0.x) + lo_bf(r1.x) + lo_bf(r2.x) + a0) * 0.25f;
        float f1 = (hi_bf(r0.x) + hi_bf(r1.x) + hi_bf(r2.x) + a1) * 0.25f;
        float f2 = (lo_bf(r0.y) + lo_bf(r1.y) + lo_bf(r2.y) + a2) * 0.25f;
        float f3 = (hi_bf(r0.y) + hi_bf(r1.y) + hi_bf(r2.y) + a3) * 0.25f;
        float f4 = (lo_bf(r0.z) + lo_bf(r1.z) + lo_bf(r2.z) + a4) * 0.25f;
        float f5 = (hi_bf(r0.z) + hi_bf(r1.z) + hi_bf(r2.z) + a5) * 0.25f;
        float f6 = (lo_bf(r0.w) + lo_bf(r1.w) + lo_bf(r2.w) + a6) * 0.25f;
        float f7 = (hi_bf(r0.w) + hi_bf(r1.w) + hi_bf(r2.w) + a7) * 0.25f;
        if (flags[0]) {
            u32x4 o;
            o.x = bf16_bits(f0) | (bf16_bits(f1) << 16);
            o.y = bf16_bits(f2) | (bf16_bits(f3) << 16);
            o.z = bf16_bits(f4) | (bf16_bits(f5) << 16);
            o.w = bf16_bits(f6) | (bf16_bits(f7) << 16);
            __builtin_nontemporal_store(
                o, reinterpret_cast<u32x4*>((__hip_bfloat16*)out + base));
        } else {
            float* op = (float*)out + base;
            u32x4 q0, q1;
            q0.x = __float_as_uint(f0); q0.y = __float_as_uint(f1);
            q0.z = __float_as_uint(f2); q0.w = __float_as_uint(f3);
            q1.x = __float_as_uint(f4); q1.y = __float_as_uint(f5);
            q1.z = __float_as_uint(f6); q1.w = __float_as_uint(f7);
            __builtin_nontemporal_store(q0, reinterpret_cast<u32x4*>(op));
            __builtin_nontemporal_store(q1, reinterpret_cast<u32x4*>(op + 4));
        }
    }
}

extern "C" void kernel_launch(void* const* d_in, const int* in_sizes, int n_in,
                              void* d_out, int out_size, void* d_ws, size_t ws_size,
                              hipStream_t stream) {
    const void* eu   = d_in[0];
    const void* ei   = d_in[1];
    const void* vals = d_in[2];
    const int*  rows = (const int*)d_in[3];
    const int*  cols = (const int*)d_in[4];
    const int nnz = in_sizes[2];

    // ws layout: h0..h2 (57.6MB) | edges (38.4MB) | tables | align8 tmp (48MB)
    __hip_bfloat16* h[3];
    h[0] = (__hip_bfloat16*)d_ws;
    h[1] = h[0] + N_ELEM;
    h[2] = h[1] + N_ELEM;
    int2* edges   = (int2*)(h[2] + N_ELEM);
    int* row_ptr  = (int*)(edges + nnz);                  // N_NODES_C + 1
    int* bktbase  = row_ptr + (N_NODES_C + 1);            // NBKT + 1
    int* tails    = bktbase + (NBKT + 1);                 // NBKT
    int* flags    = tails + NBKT;                         // 2
    char* pt = (char*)(flags + 2);
    unsigned long long* tmp =
        (unsigned long long*)(((uintptr_t)pt + 7) & ~(uintptr_t)7);  // NBKT*CAP u64

    detect_and_zero<<<1, 256, 0, stream>>>((const unsigned int*)eu,
                                           (const unsigned int*)vals, flags, tails);
    init_kernel<<<(N_ELEM + 255) / 256, 256, 0, stream>>>(eu, ei, h[0], flags);

    // CSR build: slot-bucket scatter -> bucket scan -> per-bucket CSR sort
    int nchunks = (nnz + CH_EDGES - 1) / CH_EDGES;
    scatter_bucket<<<nchunks, 256, 0, stream>>>(rows, cols, vals, tmp, tails, nnz, flags);
    scan_bkt<<<1, 512, 0, stream>>>(tails, bktbase);
    bucket_csr<<<NBKT, 512, 0, stream>>>(tmp, edges, tails, bktbase, row_ptr);

    // layers: h0 -> h1 -> h2 -> (fused final) d_out
    int nsb = (N_NODES_C + 3) / 4;
    spmm8<<<nsb, 256, 0, stream>>>(h[0], h[1], (const unsigned long long*)edges, row_ptr,
                                   nullptr, nullptr, nullptr, flags, 0);
    spmm8<<<nsb, 256, 0, stream>>>(h[1], h[2], (const unsigned long long*)edges, row_ptr,
                                   nullptr, nullptr, nullptr, flags, 0);
    spmm8<<<nsb, 256, 0, stream>>>(h[2], nullptr, (const unsigned long long*)edges, row_ptr,
                                   h[0], h[1], d_out, flags, 1);
}